// Round 1
// baseline (2364.042 us; speedup 1.0000x reference)
//
#include <hip/hip_runtime.h>

#define N_NODE   10000
#define E_EDGE   320000
#define E_LINKN  1280000
#define DIM      128
#define EFEAT    24
#define SEQLEN   64

// ---------------- workspace layout (bytes) ----------------
// zeroed region first (single memset):
static const size_t OFF_PW    = 0;                                   // [E,12] f32
static const size_t OFF_P2    = OFF_PW    + (size_t)E_EDGE*12*4;     // [E,6]  f32
static const size_t OFF_WSUM  = OFF_P2    + (size_t)E_EDGE*6*4;      // [E]    f32
static const size_t OFF_WSUM2 = OFF_WSUM  + (size_t)E_EDGE*4;        // [E]    f32
static const size_t OFF_DEG   = OFF_WSUM2 + (size_t)E_EDGE*4;        // 10240 i32
static const size_t OFF_CUR   = OFF_DEG   + 10240*4;                 // 10240 i32
static const size_t ZERO_BYTES= OFF_CUR   + 10240*4;
// non-zeroed:
static const size_t OFF_CONST = ZERO_BYTES;                          // 512 f32 (Ball 432 + cvec 24)
static const size_t OFF_V0    = OFF_CONST + 512*4;                   // [E,6]
static const size_t OFF_V12   = OFF_V0    + (size_t)E_EDGE*6*4;      // [E,12]
static const size_t OFF_WK    = OFF_V12   + (size_t)E_EDGE*12*4;     // [E,3]
static const size_t OFF_HENT  = OFF_WK    + (size_t)E_EDGE*3*4;      // [N,128]
static const size_t OFF_HA    = OFF_HENT  + (size_t)N_NODE*DIM*4;    // [N,128]
static const size_t OFF_HB    = OFF_HA    + (size_t)N_NODE*DIM*4;    // [N,128]
static const size_t OFF_START = OFF_HB    + (size_t)N_NODE*DIM*4;    // 10304 i32 (uses 10001)
static const size_t OFF_CSR   = OFF_START + 10304*4;                 // [E] i32

// ---------------- tiny-constant precompute ----------------
// A0 = (Wh0+Wh1+Wh2)Wec, A1 = -(Wh1+2Wh2)Wec, A2 = 0.5*Wh2*Wec  (each [128,6])
// Ball[i*18 + k*6 + j] = sum_r Wstart[i,r] * Ak[r,j]            ([24,18])
// cvec[k*6+j] (k<3)   = sum_r bstart[r] * Ak[r,j]
// cvec[18+j]          = bhl @ Wec + bec
__global__ void consts_kernel(const float* __restrict__ Wstart, const float* __restrict__ bstart,
                              const float* __restrict__ Whl,    const float* __restrict__ bhl,
                              const float* __restrict__ Wec,    const float* __restrict__ bec,
                              float* __restrict__ Ball, float* __restrict__ cvec) {
    __shared__ float A[3*128*6];
    int t = threadIdx.x;
    for (int idx = t; idx < 3*128*6; idx += blockDim.x) {
        int k = idx / (128*6); int rem = idx % (128*6); int r = rem / 6; int j = rem % 6;
        const float* w0 = Whl + 0*16384 + r*128;
        const float* w1 = Whl + 1*16384 + r*128;
        const float* w2 = Whl + 2*16384 + r*128;
        float s = 0.f;
        for (int d = 0; d < 128; d++) {
            float m;
            if (k == 0)      m = w0[d] + w1[d] + w2[d];
            else if (k == 1) m = -(w1[d] + 2.f*w2[d]);
            else             m = 0.5f*w2[d];
            s += m * Wec[d*6 + j];
        }
        A[idx] = s;
    }
    __syncthreads();
    for (int idx = t; idx < 24*18; idx += blockDim.x) {
        int i = idx / 18; int cj = idx % 18; int k = cj / 6; int j = cj % 6;
        float s = 0.f;
        for (int r = 0; r < 128; r++) s += Wstart[i*128 + r] * A[k*768 + r*6 + j];
        Ball[idx] = s;
    }
    for (int idx = t; idx < 24; idx += blockDim.x) {
        if (idx < 18) {
            int k = idx / 6, j = idx % 6;
            float s = 0.f;
            for (int r = 0; r < 128; r++) s += bstart[r] * A[k*768 + r*6 + j];
            cvec[idx] = s;
        } else {
            int j = idx - 18;
            float s = bec[j];
            for (int d = 0; d < 128; d++) s += bhl[d] * Wec[d*6 + j];
            cvec[idx] = s;
        }
    }
}

// V = x_link @ Ball : V0 = cols 0..5, V12 = cols 6..17
__global__ void v_kernel(const float* __restrict__ x, const float* __restrict__ Ball,
                         float* __restrict__ V0, float* __restrict__ V12) {
    __shared__ float sB[432];
    for (int i = threadIdx.x; i < 432; i += blockDim.x) sB[i] = Ball[i];
    __syncthreads();
    int e = blockIdx.x * blockDim.x + threadIdx.x;
    if (e >= E_EDGE) return;
    float xr[24];
    const float4* xp = (const float4*)(x + (size_t)e*24);
#pragma unroll
    for (int q = 0; q < 6; q++) {
        float4 v = xp[q];
        xr[4*q+0] = v.x; xr[4*q+1] = v.y; xr[4*q+2] = v.z; xr[4*q+3] = v.w;
    }
    float o[18];
#pragma unroll
    for (int j = 0; j < 18; j++) o[j] = 0.f;
#pragma unroll
    for (int i = 0; i < 24; i++) {
        float xv = xr[i];
#pragma unroll
        for (int j = 0; j < 18; j++) o[j] += xv * sB[i*18 + j];
    }
#pragma unroll
    for (int j = 0; j < 6; j++)  V0[(size_t)e*6 + j]  = o[j];
#pragma unroll
    for (int j = 0; j < 12; j++) V12[(size_t)e*12 + j] = o[6 + j];
}

// PW = P(V12) (12-wide), wsum = P(1)
__global__ void prop1_kernel(const float* __restrict__ V12, const int* __restrict__ srcl,
                             const int* __restrict__ dstl, const float* __restrict__ ew,
                             float* __restrict__ PW, float* __restrict__ wsum) {
    int e = blockIdx.x * blockDim.x + threadIdx.x;
    if (e >= E_LINKN) return;
    int s = srcl[e], d = dstl[e];
    float w = ew[e];
    const float4* vp = (const float4*)(V12 + (size_t)s*12);
    float* pw = PW + (size_t)d*12;
#pragma unroll
    for (int q = 0; q < 3; q++) {
        float4 v = vp[q];
        atomicAdd(pw + 4*q + 0, w*v.x);
        atomicAdd(pw + 4*q + 1, w*v.y);
        atomicAdd(pw + 4*q + 2, w*v.z);
        atomicAdd(pw + 4*q + 3, w*v.w);
    }
    atomicAdd(wsum + d, w);
}

// P2 = P(PW[:,6:12]) (6-wide), wsum2 = P(wsum)
__global__ void prop2_kernel(const float* __restrict__ PW, const float* __restrict__ wsum,
                             const int* __restrict__ srcl, const int* __restrict__ dstl,
                             const float* __restrict__ ew,
                             float* __restrict__ P2, float* __restrict__ wsum2) {
    int e = blockIdx.x * blockDim.x + threadIdx.x;
    if (e >= E_LINKN) return;
    int s = srcl[e], d = dstl[e];
    float w = ew[e];
    const float2* pv = (const float2*)(PW + (size_t)s*12 + 6);
    float* p2 = P2 + (size_t)d*6;
#pragma unroll
    for (int q = 0; q < 3; q++) {
        float2 v = pv[q];
        atomicAdd(p2 + 2*q + 0, w*v.x);
        atomicAdd(p2 + 2*q + 1, w*v.y);
    }
    atomicAdd(wsum2 + d, w * wsum[s]);
}

// S = V0 + c0 + PW[:, :6] + wsum*c1 + P2 + wsum2*c2 + c ; wk = sigmoid(S[2k]-S[2k+1])
__global__ void score_kernel(const float* __restrict__ V0, const float* __restrict__ PW,
                             const float* __restrict__ P2, const float* __restrict__ wsum,
                             const float* __restrict__ wsum2, const float* __restrict__ cvec,
                             float* __restrict__ wk) {
    __shared__ float sc[24];
    if (threadIdx.x < 24) sc[threadIdx.x] = cvec[threadIdx.x];
    __syncthreads();
    int e = blockIdx.x * blockDim.x + threadIdx.x;
    if (e >= E_EDGE) return;
    float ws1 = wsum[e], ws2 = wsum2[e];
    float S[6];
#pragma unroll
    for (int j = 0; j < 6; j++)
        S[j] = V0[(size_t)e*6 + j] + PW[(size_t)e*12 + j] + P2[(size_t)e*6 + j]
             + ws1*sc[6 + j] + ws2*sc[12 + j] + sc[j] + sc[18 + j];
#pragma unroll
    for (int k = 0; k < 3; k++)
        wk[(size_t)e*3 + k] = 1.f / (1.f + __expf(S[2*k+1] - S[2*k]));
}

// ---------------- node CSR build ----------------
__global__ void hist_kernel(const int* __restrict__ dstn, int* __restrict__ deg) {
    int e = blockIdx.x * blockDim.x + threadIdx.x;
    if (e < E_EDGE) atomicAdd(deg + dstn[e], 1);
}

__global__ void scan_kernel(const int* __restrict__ deg, int* __restrict__ start, int n) {
    __shared__ int part[1024];
    int t = threadIdx.x;
    const int CH = (n + 1023) / 1024;
    int base = t * CH;
    int s = 0;
    for (int i = 0; i < CH; i++) { int idx = base + i; if (idx < n) s += deg[idx]; }
    part[t] = s;
    __syncthreads();
    for (int off = 1; off < 1024; off <<= 1) {
        int v = (t >= off) ? part[t - off] : 0;
        __syncthreads();
        part[t] += v;
        __syncthreads();
    }
    int run = (t == 0) ? 0 : part[t - 1];
    for (int i = 0; i < CH; i++) {
        int idx = base + i;
        if (idx < n) { start[idx] = run; run += deg[idx]; }
    }
    if (t == 1023) start[n] = part[1023];
}

__global__ void fill_kernel(const int* __restrict__ dstn, const int* __restrict__ start,
                            int* __restrict__ cursor, int* __restrict__ csr) {
    int e = blockIdx.x * blockDim.x + threadIdx.x;
    if (e >= E_EDGE) return;
    int d = dstn[e];
    int p = start[d] + atomicAdd(cursor + d, 1);
    csr[p] = e;
}

// ---------------- temporal projection ----------------
// h_ent[n,d] = sum_t Wt[t]*h_entity[t,n,d] + bt
__global__ void temporal_kernel(const float4* __restrict__ h_entity, const float* __restrict__ Wt,
                                const float* __restrict__ bt, float4* __restrict__ h_ent) {
    __shared__ float sw[SEQLEN];
    if (threadIdx.x < SEQLEN) sw[threadIdx.x] = Wt[threadIdx.x];
    __syncthreads();
    int i = blockIdx.x * blockDim.x + threadIdx.x;            // over N*D/4 = 320000
    if (i >= N_NODE*DIM/4) return;
    float b = bt[0];
    float4 acc = make_float4(b, b, b, b);
#pragma unroll 8
    for (int t = 0; t < SEQLEN; t++) {
        float4 v = h_entity[(size_t)t * (N_NODE*DIM/4) + i];
        float w = sw[t];
        acc.x += w*v.x; acc.y += w*v.y; acc.z += w*v.z; acc.w += w*v.w;
    }
    h_ent[i] = acc;
}

// ---------------- fused GCN hop: h_next = P_k(h_cur); out (+)= h_next @ G_k (+ b_gcn if first)
__global__ void hop_kernel(const float* __restrict__ h_cur, float* __restrict__ h_next,
                           float* __restrict__ out,
                           const int* __restrict__ csr, const int* __restrict__ start,
                           const int* __restrict__ srcn, const float* __restrict__ wk, int k,
                           const float* __restrict__ G, const float* __restrict__ bgcn, int first) {
    int node = blockIdx.x;
    int tid  = threadIdx.x;          // 128
    int s0 = start[node], s1 = start[node + 1];
    float acc = 0.f;
    for (int j = s0; j < s1; j++) {
        int e = csr[j];
        float w = wk[(size_t)e*3 + k];
        int sn = srcn[e];
        acc += w * h_cur[(size_t)sn*DIM + tid];
    }
    h_next[(size_t)node*DIM + tid] = acc;
    __shared__ float hrow[DIM];
    hrow[tid] = acc;
    __syncthreads();
    float o = first ? bgcn[tid] : out[(size_t)node*DIM + tid];
#pragma unroll 8
    for (int d = 0; d < DIM; d++) o += hrow[d] * G[d*DIM + tid];
    out[(size_t)node*DIM + tid] = o;
}

extern "C" void kernel_launch(void* const* d_in, const int* in_sizes, int n_in,
                              void* d_out, int out_size, void* d_ws, size_t ws_size,
                              hipStream_t stream) {
    const float* h_entity = (const float*)d_in[0];
    const float* x_link   = (const float*)d_in[1];
    const float* ewl      = (const float*)d_in[2];
    const int*   eil      = (const int*)d_in[3];
    const int*   ein      = (const int*)d_in[4];
    const float* Wstart   = (const float*)d_in[5];
    const float* bstart   = (const float*)d_in[6];
    const float* Whl      = (const float*)d_in[7];
    const float* bhl      = (const float*)d_in[8];
    const float* Wec      = (const float*)d_in[9];
    const float* bec      = (const float*)d_in[10];
    const float* Wt       = (const float*)d_in[11];
    const float* bt       = (const float*)d_in[12];
    const float* Wgcn     = (const float*)d_in[13];
    const float* bgcn     = (const float*)d_in[14];
    float* out = (float*)d_out;
    char*  ws  = (char*)d_ws;

    const int* srcl = eil;
    const int* dstl = eil + E_LINKN;
    const int* srcn = ein;
    const int* dstn = ein + E_EDGE;

    float* PW    = (float*)(ws + OFF_PW);
    float* P2b   = (float*)(ws + OFF_P2);
    float* wsum  = (float*)(ws + OFF_WSUM);
    float* wsum2 = (float*)(ws + OFF_WSUM2);
    int*   deg   = (int*)  (ws + OFF_DEG);
    int*   cur   = (int*)  (ws + OFF_CUR);
    float* Ball  = (float*)(ws + OFF_CONST);
    float* cvec  = Ball + 432;
    float* V0    = (float*)(ws + OFF_V0);
    float* V12   = (float*)(ws + OFF_V12);
    float* wk    = (float*)(ws + OFF_WK);
    float* h_ent = (float*)(ws + OFF_HENT);
    float* h_a   = (float*)(ws + OFF_HA);
    float* h_b   = (float*)(ws + OFF_HB);
    int*   startp= (int*)  (ws + OFF_START);
    int*   csr   = (int*)  (ws + OFF_CSR);

    hipMemsetAsync(ws, 0, ZERO_BYTES, stream);

    consts_kernel<<<1, 256, 0, stream>>>(Wstart, bstart, Whl, bhl, Wec, bec, Ball, cvec);
    v_kernel<<<(E_EDGE + 255)/256, 256, 0, stream>>>(x_link, Ball, V0, V12);
    prop1_kernel<<<(E_LINKN + 255)/256, 256, 0, stream>>>(V12, srcl, dstl, ewl, PW, wsum);
    prop2_kernel<<<(E_LINKN + 255)/256, 256, 0, stream>>>(PW, wsum, srcl, dstl, ewl, P2b, wsum2);
    score_kernel<<<(E_EDGE + 255)/256, 256, 0, stream>>>(V0, PW, P2b, wsum, wsum2, cvec, wk);

    hist_kernel<<<(E_EDGE + 255)/256, 256, 0, stream>>>(dstn, deg);
    scan_kernel<<<1, 1024, 0, stream>>>(deg, startp, N_NODE);
    fill_kernel<<<(E_EDGE + 255)/256, 256, 0, stream>>>(dstn, startp, cur, csr);

    temporal_kernel<<<(N_NODE*DIM/4 + 255)/256, 256, 0, stream>>>(
        (const float4*)h_entity, Wt, bt, (float4*)h_ent);

    hop_kernel<<<N_NODE, DIM, 0, stream>>>(h_ent, h_a, out, csr, startp, srcn, wk, 0,
                                           Wgcn + 0*16384, bgcn, 1);
    hop_kernel<<<N_NODE, DIM, 0, stream>>>(h_a, h_b, out, csr, startp, srcn, wk, 1,
                                           Wgcn + 1*16384, bgcn, 0);
    hop_kernel<<<N_NODE, DIM, 0, stream>>>(h_b, h_ent, out, csr, startp, srcn, wk, 2,
                                           Wgcn + 2*16384, bgcn, 0);
}

// Round 2
// 1864.007 us; speedup vs baseline: 1.2683x; 1.2683x over previous
//
#include <hip/hip_runtime.h>

#define N_NODE   10000
#define E_EDGE   320000
#define E_LINKN  1280000
#define DIM      128
#define EFEAT    24
#define SEQLEN   64

// ---------------- workspace layout (bytes) ----------------
// zeroed region first (single memset): histograms + cursors for both CSR builds
static const size_t OFF_DEGN  = 0;                                    // 10240 i32
static const size_t OFF_CURN  = OFF_DEGN  + 10240*4;                  // 10240 i32
static const size_t OFF_DEGL  = OFF_CURN  + 10240*4;                  // E_EDGE i32
static const size_t OFF_CURL  = OFF_DEGL  + (size_t)E_EDGE*4;         // E_EDGE i32
static const size_t ZERO_BYTES= OFF_CURL  + (size_t)E_EDGE*4;
// non-zeroed:
static const size_t OFF_CONST = ZERO_BYTES;                           // 512 f32 (Ball 432 + cvec 24)
static const size_t OFF_V0    = OFF_CONST + 512*4;                    // [E,6]  f32
static const size_t OFF_V12   = OFF_V0    + (size_t)E_EDGE*6*4;       // [E,12] f32
static const size_t OFF_PW    = OFF_V12   + (size_t)E_EDGE*12*4;      // [E,12] f32
static const size_t OFF_WSUM  = OFF_PW    + (size_t)E_EDGE*12*4;      // [E]    f32
static const size_t OFF_STARTN= OFF_WSUM  + (size_t)E_EDGE*4;         // 10304 i32 (uses 10001)
static const size_t OFF_SRCSN = OFF_STARTN+ 10304*4;                  // [E] i32 (CSR-sorted src node)
static const size_t OFF_POSN  = OFF_SRCSN + (size_t)E_EDGE*4;         // [E] i32 (edge -> CSR slot)
static const size_t OFF_WKS   = OFF_POSN  + (size_t)E_EDGE*4;         // [E,3] f32 (CSR-sorted wk)
static const size_t OFF_STARTL= OFF_WKS   + (size_t)E_EDGE*3*4;       // E_EDGE+64 i32
static const size_t OFF_SRCSL = OFF_STARTL+ ((size_t)E_EDGE+64)*4;    // [E_LINK] i32 (sorted src)
static const size_t OFF_WL    = OFF_SRCSL + (size_t)E_LINKN*4;        // [E_LINK] f32 (sorted w)
static const size_t OFF_HENT  = OFF_WL    + (size_t)E_LINKN*4;        // [N,128]
static const size_t OFF_HA    = OFF_HENT  + (size_t)N_NODE*DIM*4;     // [N,128]
static const size_t OFF_HB    = OFF_HA    + (size_t)N_NODE*DIM*4;     // [N,128]

// ---------------- tiny-constant precompute ----------------
// A0 = (Wh0+Wh1+Wh2)Wec, A1 = -(Wh1+2Wh2)Wec, A2 = 0.5*Wh2*Wec  (each [128,6])
// Ball[i*18 + k*6 + j] = sum_r Wstart[i,r] * Ak[r,j]            ([24,18])
// cvec[k*6+j] (k<3)   = sum_r bstart[r] * Ak[r,j]
// cvec[18+j]          = bhl @ Wec + bec
__global__ void consts_kernel(const float* __restrict__ Wstart, const float* __restrict__ bstart,
                              const float* __restrict__ Whl,    const float* __restrict__ bhl,
                              const float* __restrict__ Wec,    const float* __restrict__ bec,
                              float* __restrict__ Ball, float* __restrict__ cvec) {
    __shared__ float A[3*128*6];
    int t = threadIdx.x;
    for (int idx = t; idx < 3*128*6; idx += blockDim.x) {
        int k = idx / (128*6); int rem = idx % (128*6); int r = rem / 6; int j = rem % 6;
        const float* w0 = Whl + 0*16384 + r*128;
        const float* w1 = Whl + 1*16384 + r*128;
        const float* w2 = Whl + 2*16384 + r*128;
        float s = 0.f;
        for (int d = 0; d < 128; d++) {
            float m;
            if (k == 0)      m = w0[d] + w1[d] + w2[d];
            else if (k == 1) m = -(w1[d] + 2.f*w2[d]);
            else             m = 0.5f*w2[d];
            s += m * Wec[d*6 + j];
        }
        A[idx] = s;
    }
    __syncthreads();
    for (int idx = t; idx < 24*18; idx += blockDim.x) {
        int i = idx / 18; int cj = idx % 18; int k = cj / 6; int j = cj % 6;
        float s = 0.f;
        for (int r = 0; r < 128; r++) s += Wstart[i*128 + r] * A[k*768 + r*6 + j];
        Ball[idx] = s;
    }
    for (int idx = t; idx < 24; idx += blockDim.x) {
        if (idx < 18) {
            int k = idx / 6, j = idx % 6;
            float s = 0.f;
            for (int r = 0; r < 128; r++) s += bstart[r] * A[k*768 + r*6 + j];
            cvec[idx] = s;
        } else {
            int j = idx - 18;
            float s = bec[j];
            for (int d = 0; d < 128; d++) s += bhl[d] * Wec[d*6 + j];
            cvec[idx] = s;
        }
    }
}

// V = x_link @ Ball : V0 = cols 0..5, V12 = cols 6..17
__global__ void v_kernel(const float* __restrict__ x, const float* __restrict__ Ball,
                         float* __restrict__ V0, float* __restrict__ V12) {
    __shared__ float sB[432];
    for (int i = threadIdx.x; i < 432; i += blockDim.x) sB[i] = Ball[i];
    __syncthreads();
    int e = blockIdx.x * blockDim.x + threadIdx.x;
    if (e >= E_EDGE) return;
    float xr[24];
    const float4* xp = (const float4*)(x + (size_t)e*24);
#pragma unroll
    for (int q = 0; q < 6; q++) {
        float4 v = xp[q];
        xr[4*q+0] = v.x; xr[4*q+1] = v.y; xr[4*q+2] = v.z; xr[4*q+3] = v.w;
    }
    float o[18];
#pragma unroll
    for (int j = 0; j < 18; j++) o[j] = 0.f;
#pragma unroll
    for (int i = 0; i < 24; i++) {
        float xv = xr[i];
#pragma unroll
        for (int j = 0; j < 18; j++) o[j] += xv * sB[i*18 + j];
    }
#pragma unroll
    for (int j = 0; j < 6; j++)  V0[(size_t)e*6 + j]  = o[j];
#pragma unroll
    for (int j = 0; j < 12; j++) V12[(size_t)e*12 + j] = o[6 + j];
}

// ---------------- CSR builds (node graph: E edges -> N_NODE bins; link graph: E_LINK -> E bins)
__global__ void hist_kernel(const int* __restrict__ dst, int* __restrict__ deg, int n) {
    int e = blockIdx.x * blockDim.x + threadIdx.x;
    if (e < n) atomicAdd(deg + dst[e], 1);
}

__global__ void scan_kernel(const int* __restrict__ deg, int* __restrict__ start, int n) {
    __shared__ int part[1024];
    int t = threadIdx.x;
    const int CH = (n + 1023) / 1024;
    int base = t * CH;
    int s = 0;
    for (int i = 0; i < CH; i++) { int idx = base + i; if (idx < n) s += deg[idx]; }
    part[t] = s;
    __syncthreads();
    for (int off = 1; off < 1024; off <<= 1) {
        int v = (t >= off) ? part[t - off] : 0;
        __syncthreads();
        part[t] += v;
        __syncthreads();
    }
    int run = (t == 0) ? 0 : part[t - 1];
    for (int i = 0; i < CH; i++) {
        int idx = base + i;
        if (idx < n) { start[idx] = run; run += deg[idx]; }
    }
    if (t == 1023) start[n] = part[1023];
}

// node-graph fill: store sorted src and edge->slot map (wk gets written sorted later)
__global__ void fill_n_kernel(const int* __restrict__ srcn, const int* __restrict__ dstn,
                              const int* __restrict__ start, int* __restrict__ cursor,
                              int* __restrict__ srcs_srt, int* __restrict__ pos) {
    int e = blockIdx.x * blockDim.x + threadIdx.x;
    if (e >= E_EDGE) return;
    int d = dstn[e];
    int p = start[d] + atomicAdd(cursor + d, 1);
    srcs_srt[p] = srcn[e];
    pos[e] = p;
}

// link-graph fill: store packed (src, w) in CSR order
__global__ void fill_l_kernel(const int* __restrict__ srcl, const int* __restrict__ dstl,
                              const float* __restrict__ ew,
                              const int* __restrict__ start, int* __restrict__ cursor,
                              int* __restrict__ srcs_srt, float* __restrict__ w_srt) {
    int e = blockIdx.x * blockDim.x + threadIdx.x;
    if (e >= E_LINKN) return;
    int d = dstl[e];
    int p = start[d] + atomicAdd(cursor + d, 1);
    srcs_srt[p] = srcl[e];
    w_srt[p] = ew[e];
}

// PW[e] = sum_links w*V12[src], wsum[e] = sum w   (pure gather, no atomics)
__global__ void prop1_gather(const float* __restrict__ V12, const int* __restrict__ startl,
                             const int* __restrict__ srcsl, const float* __restrict__ wl,
                             float* __restrict__ PW, float* __restrict__ wsum) {
    int e = blockIdx.x * blockDim.x + threadIdx.x;
    if (e >= E_EDGE) return;
    int s0 = startl[e], s1 = startl[e + 1];
    float acc[12];
#pragma unroll
    for (int j = 0; j < 12; j++) acc[j] = 0.f;
    float ws = 0.f;
    for (int j = s0; j < s1; j++) {
        int s = srcsl[j];
        float w = wl[j];
        const float4* vp = (const float4*)(V12 + (size_t)s*12);
#pragma unroll
        for (int q = 0; q < 3; q++) {
            float4 v = vp[q];
            acc[4*q+0] += w*v.x; acc[4*q+1] += w*v.y;
            acc[4*q+2] += w*v.z; acc[4*q+3] += w*v.w;
        }
        ws += w;
    }
    float4* pw = (float4*)(PW + (size_t)e*12);
#pragma unroll
    for (int q = 0; q < 3; q++)
        pw[q] = make_float4(acc[4*q+0], acc[4*q+1], acc[4*q+2], acc[4*q+3]);
    wsum[e] = ws;
}

// fused: gather P2/wsum2, combine with V0 + PW[:, :6] + wsum, sigmoid -> wk (CSR-sorted write)
__global__ void prop2score_kernel(const float* __restrict__ PW, const float* __restrict__ wsum,
                                  const int* __restrict__ startl, const int* __restrict__ srcsl,
                                  const float* __restrict__ wl, const float* __restrict__ V0,
                                  const float* __restrict__ cvec, const int* __restrict__ posn,
                                  float* __restrict__ wks) {
    __shared__ float sc[24];
    if (threadIdx.x < 24) sc[threadIdx.x] = cvec[threadIdx.x];
    __syncthreads();
    int e = blockIdx.x * blockDim.x + threadIdx.x;
    if (e >= E_EDGE) return;
    int s0 = startl[e], s1 = startl[e + 1];
    float p2[6];
#pragma unroll
    for (int j = 0; j < 6; j++) p2[j] = 0.f;
    float ws2 = 0.f;
    for (int j = s0; j < s1; j++) {
        int s = srcsl[j];
        float w = wl[j];
        const float2* pv = (const float2*)(PW + (size_t)s*12 + 6);
#pragma unroll
        for (int q = 0; q < 3; q++) {
            float2 v = pv[q];
            p2[2*q+0] += w*v.x; p2[2*q+1] += w*v.y;
        }
        ws2 += w * wsum[s];
    }
    float ws1 = wsum[e];
    float S[6];
#pragma unroll
    for (int j = 0; j < 6; j++)
        S[j] = V0[(size_t)e*6 + j] + PW[(size_t)e*12 + j] + p2[j]
             + ws1*sc[6 + j] + ws2*sc[12 + j] + sc[j] + sc[18 + j];
    int p = posn[e];
#pragma unroll
    for (int k = 0; k < 3; k++)
        wks[(size_t)p*3 + k] = 1.f / (1.f + __expf(S[2*k+1] - S[2*k]));
}

// ---------------- temporal projection ----------------
// h_ent[n,d] = sum_t Wt[t]*h_entity[t,n,d] + bt
__global__ void temporal_kernel(const float4* __restrict__ h_entity, const float* __restrict__ Wt,
                                const float* __restrict__ bt, float4* __restrict__ h_ent) {
    __shared__ float sw[SEQLEN];
    if (threadIdx.x < SEQLEN) sw[threadIdx.x] = Wt[threadIdx.x];
    __syncthreads();
    int i = blockIdx.x * blockDim.x + threadIdx.x;            // over N*D/4 = 320000
    if (i >= N_NODE*DIM/4) return;
    float b = bt[0];
    float4 acc = make_float4(b, b, b, b);
#pragma unroll 8
    for (int t = 0; t < SEQLEN; t++) {
        float4 v = h_entity[(size_t)t * (N_NODE*DIM/4) + i];
        float w = sw[t];
        acc.x += w*v.x; acc.y += w*v.y; acc.z += w*v.z; acc.w += w*v.w;
    }
    h_ent[i] = acc;
}

// ---------------- fused GCN hop: h_next = P_k(h_cur); out (+)= h_next @ G_k (+ b_gcn if first)
__global__ void hop_kernel(const float* __restrict__ h_cur, float* __restrict__ h_next,
                           float* __restrict__ out,
                           const int* __restrict__ startn, const int* __restrict__ srcs_srt,
                           const float* __restrict__ wks, int k,
                           const float* __restrict__ G, const float* __restrict__ bgcn, int first) {
    int node = blockIdx.x;
    int tid  = threadIdx.x;          // 128
    int s0 = startn[node], s1 = startn[node + 1];
    float acc = 0.f;
    for (int j = s0; j < s1; j++) {
        float w = wks[(size_t)j*3 + k];
        int sn = srcs_srt[j];
        acc += w * h_cur[(size_t)sn*DIM + tid];
    }
    h_next[(size_t)node*DIM + tid] = acc;
    __shared__ float hrow[DIM];
    hrow[tid] = acc;
    __syncthreads();
    float o = first ? bgcn[tid] : out[(size_t)node*DIM + tid];
#pragma unroll 8
    for (int d = 0; d < DIM; d++) o += hrow[d] * G[d*DIM + tid];
    out[(size_t)node*DIM + tid] = o;
}

extern "C" void kernel_launch(void* const* d_in, const int* in_sizes, int n_in,
                              void* d_out, int out_size, void* d_ws, size_t ws_size,
                              hipStream_t stream) {
    const float* h_entity = (const float*)d_in[0];
    const float* x_link   = (const float*)d_in[1];
    const float* ewl      = (const float*)d_in[2];
    const int*   eil      = (const int*)d_in[3];
    const int*   ein      = (const int*)d_in[4];
    const float* Wstart   = (const float*)d_in[5];
    const float* bstart   = (const float*)d_in[6];
    const float* Whl      = (const float*)d_in[7];
    const float* bhl      = (const float*)d_in[8];
    const float* Wec      = (const float*)d_in[9];
    const float* bec      = (const float*)d_in[10];
    const float* Wt       = (const float*)d_in[11];
    const float* bt       = (const float*)d_in[12];
    const float* Wgcn     = (const float*)d_in[13];
    const float* bgcn     = (const float*)d_in[14];
    float* out = (float*)d_out;
    char*  ws  = (char*)d_ws;

    const int* srcl = eil;
    const int* dstl = eil + E_LINKN;
    const int* srcn = ein;
    const int* dstn = ein + E_EDGE;

    int*   degn  = (int*)  (ws + OFF_DEGN);
    int*   curn  = (int*)  (ws + OFF_CURN);
    int*   degl  = (int*)  (ws + OFF_DEGL);
    int*   curl  = (int*)  (ws + OFF_CURL);
    float* Ball  = (float*)(ws + OFF_CONST);
    float* cvec  = Ball + 432;
    float* V0    = (float*)(ws + OFF_V0);
    float* V12   = (float*)(ws + OFF_V12);
    float* PW    = (float*)(ws + OFF_PW);
    float* wsum  = (float*)(ws + OFF_WSUM);
    int*   startn= (int*)  (ws + OFF_STARTN);
    int*   srcsn = (int*)  (ws + OFF_SRCSN);
    int*   posn  = (int*)  (ws + OFF_POSN);
    float* wks   = (float*)(ws + OFF_WKS);
    int*   startl= (int*)  (ws + OFF_STARTL);
    int*   srcsl = (int*)  (ws + OFF_SRCSL);
    float* wl    = (float*)(ws + OFF_WL);
    float* h_ent = (float*)(ws + OFF_HENT);
    float* h_a   = (float*)(ws + OFF_HA);
    float* h_b   = (float*)(ws + OFF_HB);

    hipMemsetAsync(ws, 0, ZERO_BYTES, stream);

    consts_kernel<<<1, 256, 0, stream>>>(Wstart, bstart, Whl, bhl, Wec, bec, Ball, cvec);
    v_kernel<<<(E_EDGE + 255)/256, 256, 0, stream>>>(x_link, Ball, V0, V12);

    // CSR builds
    hist_kernel<<<(E_EDGE + 255)/256, 256, 0, stream>>>(dstn, degn, E_EDGE);
    hist_kernel<<<(E_LINKN + 255)/256, 256, 0, stream>>>(dstl, degl, E_LINKN);
    scan_kernel<<<1, 1024, 0, stream>>>(degn, startn, N_NODE);
    scan_kernel<<<1, 1024, 0, stream>>>(degl, startl, E_EDGE);
    fill_n_kernel<<<(E_EDGE + 255)/256, 256, 0, stream>>>(srcn, dstn, startn, curn, srcsn, posn);
    fill_l_kernel<<<(E_LINKN + 255)/256, 256, 0, stream>>>(srcl, dstl, ewl, startl, curl, srcsl, wl);

    // link-graph propagates (gather)
    prop1_gather<<<(E_EDGE + 255)/256, 256, 0, stream>>>(V12, startl, srcsl, wl, PW, wsum);
    prop2score_kernel<<<(E_EDGE + 255)/256, 256, 0, stream>>>(PW, wsum, startl, srcsl, wl,
                                                             V0, cvec, posn, wks);

    temporal_kernel<<<(N_NODE*DIM/4 + 255)/256, 256, 0, stream>>>(
        (const float4*)h_entity, Wt, bt, (float4*)h_ent);

    hop_kernel<<<N_NODE, DIM, 0, stream>>>(h_ent, h_a, out, startn, srcsn, wks, 0,
                                           Wgcn + 0*16384, bgcn, 1);
    hop_kernel<<<N_NODE, DIM, 0, stream>>>(h_a, h_b, out, startn, srcsn, wks, 1,
                                           Wgcn + 1*16384, bgcn, 0);
    hop_kernel<<<N_NODE, DIM, 0, stream>>>(h_b, h_ent, out, startn, srcsn, wks, 2,
                                           Wgcn + 2*16384, bgcn, 0);
}

// Round 3
// 1206.275 us; speedup vs baseline: 1.9598x; 1.5453x over previous
//
#include <hip/hip_runtime.h>

#define N_NODE   10000
#define E_EDGE   320000
#define E_LINKN  1280000
#define DIM      128
#define EFEAT    24
#define SEQLEN   64

#define SCAN_CHUNK 4096   // elements per block in hierarchical scan

// ---------------- workspace layout (bytes) ----------------
// zeroed region first (single memset): histograms + cursors for both CSR builds
static const size_t OFF_DEGN  = 0;                                    // 10240 i32
static const size_t OFF_CURN  = OFF_DEGN  + 10240*4;                  // 10240 i32
static const size_t OFF_DEGL  = OFF_CURN  + 10240*4;                  // E_EDGE i32
static const size_t OFF_CURL  = OFF_DEGL  + (size_t)E_EDGE*4;         // E_EDGE i32
static const size_t ZERO_BYTES= OFF_CURL  + (size_t)E_EDGE*4;
// non-zeroed:
static const size_t OFF_CONST = ZERO_BYTES;                           // 512 f32 (Ball 432 + cvec 24)
static const size_t OFF_V0    = OFF_CONST + 512*4;                    // [E,6]  f32
static const size_t OFF_V12   = OFF_V0    + (size_t)E_EDGE*6*4;       // [E,12] f32
static const size_t OFF_PW    = OFF_V12   + (size_t)E_EDGE*12*4;      // [E,12] f32
static const size_t OFF_WSUM  = OFF_PW    + (size_t)E_EDGE*12*4;      // [E]    f32
static const size_t OFF_STARTN= OFF_WSUM  + (size_t)E_EDGE*4;         // 10304 i32 (uses 10001)
static const size_t OFF_SRCSN = OFF_STARTN+ 10304*4;                  // [E] i32 (CSR-sorted src node)
static const size_t OFF_POSN  = OFF_SRCSN + (size_t)E_EDGE*4;         // [E] i32 (edge -> CSR slot)
static const size_t OFF_WKS   = OFF_POSN  + (size_t)E_EDGE*4;         // [E,3] f32 (CSR-sorted wk)
static const size_t OFF_STARTL= OFF_WKS   + (size_t)E_EDGE*3*4;       // E_EDGE+64 i32
static const size_t OFF_SRCSL = OFF_STARTL+ ((size_t)E_EDGE+64)*4;    // [E_LINK] i32 (sorted src)
static const size_t OFF_WL    = OFF_SRCSL + (size_t)E_LINKN*4;        // [E_LINK] f32 (sorted w)
static const size_t OFF_HENT  = OFF_WL    + (size_t)E_LINKN*4;        // [N,128]
static const size_t OFF_HA    = OFF_HENT  + (size_t)N_NODE*DIM*4;     // [N,128]
static const size_t OFF_HB    = OFF_HA    + (size_t)N_NODE*DIM*4;     // [N,128]
static const size_t OFF_PARTN = OFF_HB    + (size_t)N_NODE*DIM*4;     // 512 i32 (partials+offs, node)
static const size_t OFF_PARTL = OFF_PARTN + 512*4;                    // 512 i32 (partials+offs, link)

// ---------------- tiny-constant precompute ----------------
__global__ void consts_kernel(const float* __restrict__ Wstart, const float* __restrict__ bstart,
                              const float* __restrict__ Whl,    const float* __restrict__ bhl,
                              const float* __restrict__ Wec,    const float* __restrict__ bec,
                              float* __restrict__ Ball, float* __restrict__ cvec) {
    __shared__ float A[3*128*6];
    int t = threadIdx.x;
    for (int idx = t; idx < 3*128*6; idx += blockDim.x) {
        int k = idx / (128*6); int rem = idx % (128*6); int r = rem / 6; int j = rem % 6;
        const float* w0 = Whl + 0*16384 + r*128;
        const float* w1 = Whl + 1*16384 + r*128;
        const float* w2 = Whl + 2*16384 + r*128;
        float s = 0.f;
        for (int d = 0; d < 128; d++) {
            float m;
            if (k == 0)      m = w0[d] + w1[d] + w2[d];
            else if (k == 1) m = -(w1[d] + 2.f*w2[d]);
            else             m = 0.5f*w2[d];
            s += m * Wec[d*6 + j];
        }
        A[idx] = s;
    }
    __syncthreads();
    for (int idx = t; idx < 24*18; idx += blockDim.x) {
        int i = idx / 18; int cj = idx % 18; int k = cj / 6; int j = cj % 6;
        float s = 0.f;
        for (int r = 0; r < 128; r++) s += Wstart[i*128 + r] * A[k*768 + r*6 + j];
        Ball[idx] = s;
    }
    for (int idx = t; idx < 24; idx += blockDim.x) {
        if (idx < 18) {
            int k = idx / 6, j = idx % 6;
            float s = 0.f;
            for (int r = 0; r < 128; r++) s += bstart[r] * A[k*768 + r*6 + j];
            cvec[idx] = s;
        } else {
            int j = idx - 18;
            float s = bec[j];
            for (int d = 0; d < 128; d++) s += bhl[d] * Wec[d*6 + j];
            cvec[idx] = s;
        }
    }
}

// V = x_link @ Ball : V0 = cols 0..5, V12 = cols 6..17
__global__ void v_kernel(const float* __restrict__ x, const float* __restrict__ Ball,
                         float* __restrict__ V0, float* __restrict__ V12) {
    __shared__ float sB[432];
    for (int i = threadIdx.x; i < 432; i += blockDim.x) sB[i] = Ball[i];
    __syncthreads();
    int e = blockIdx.x * blockDim.x + threadIdx.x;
    if (e >= E_EDGE) return;
    float xr[24];
    const float4* xp = (const float4*)(x + (size_t)e*24);
#pragma unroll
    for (int q = 0; q < 6; q++) {
        float4 v = xp[q];
        xr[4*q+0] = v.x; xr[4*q+1] = v.y; xr[4*q+2] = v.z; xr[4*q+3] = v.w;
    }
    float o[18];
#pragma unroll
    for (int j = 0; j < 18; j++) o[j] = 0.f;
#pragma unroll
    for (int i = 0; i < 24; i++) {
        float xv = xr[i];
#pragma unroll
        for (int j = 0; j < 18; j++) o[j] += xv * sB[i*18 + j];
    }
#pragma unroll
    for (int j = 0; j < 6; j++)  V0[(size_t)e*6 + j]  = o[j];
#pragma unroll
    for (int j = 0; j < 12; j++) V12[(size_t)e*12 + j] = o[6 + j];
}

// ---------------- CSR builds ----------------
__global__ void hist_kernel(const int* __restrict__ dst, int* __restrict__ deg, int n) {
    int e = blockIdx.x * blockDim.x + threadIdx.x;
    if (e < n) atomicAdd(deg + dst[e], 1);
}

// ---- hierarchical exclusive scan: phase 1 (per-block sums, coalesced) ----
__global__ void partial_kernel(const int* __restrict__ deg, int* __restrict__ partials, int n) {
    __shared__ int red[256];
    int b = blockIdx.x, t = threadIdx.x;
    int base = b * SCAN_CHUNK;
    int s = 0;
    for (int i = t; i < SCAN_CHUNK; i += 256) {
        int idx = base + i;
        if (idx < n) s += deg[idx];
    }
    red[t] = s;
    __syncthreads();
    for (int off = 128; off > 0; off >>= 1) {
        if (t < off) red[t] += red[t + off];
        __syncthreads();
    }
    if (t == 0) partials[b] = red[0];
}

// ---- phase 2: scan of block partials (nb <= 256), writes offs[] and start[n]=total ----
__global__ void scan_partials_kernel(const int* __restrict__ partials, int* __restrict__ offs,
                                     int* __restrict__ start, int nb, int n) {
    __shared__ int a[256];
    int t = threadIdx.x;
    a[t] = (t < nb) ? partials[t] : 0;
    __syncthreads();
    for (int off = 1; off < 256; off <<= 1) {
        int v = (t >= off) ? a[t - off] : 0;
        __syncthreads();
        a[t] += v;
        __syncthreads();
    }
    offs[t] = (t == 0) ? 0 : a[t - 1];
    if (t == 255) start[n] = a[nb - 1];
}

// ---- phase 3: per-block exclusive scan + global offset, coalesced in/out ----
__global__ void scan_block_kernel(const int* __restrict__ deg, const int* __restrict__ offs,
                                  int* __restrict__ start, int n) {
    __shared__ int s[SCAN_CHUNK];
    __shared__ int tsum[256];
    int b = blockIdx.x, t = threadIdx.x;
    int base = b * SCAN_CHUNK;
    for (int i = t; i < SCAN_CHUNK; i += 256) {
        int idx = base + i;
        s[i] = (idx < n) ? deg[idx] : 0;
    }
    __syncthreads();
    // per-thread serial sum of its 16 contiguous elements
    int lo = t * 16;
    int mysum = 0;
#pragma unroll
    for (int j = 0; j < 16; j++) mysum += s[lo + j];
    tsum[t] = mysum;
    __syncthreads();
    for (int off = 1; off < 256; off <<= 1) {
        int v = (t >= off) ? tsum[t - off] : 0;
        __syncthreads();
        tsum[t] += v;
        __syncthreads();
    }
    int run = offs[b] + ((t == 0) ? 0 : tsum[t - 1]);
#pragma unroll
    for (int j = 0; j < 16; j++) {
        int v = s[lo + j];
        s[lo + j] = run;
        run += v;
    }
    __syncthreads();
    for (int i = t; i < SCAN_CHUNK; i += 256) {
        int idx = base + i;
        if (idx < n) start[idx] = s[i];
    }
}

// node-graph fill: store sorted src and edge->slot map (wk gets written sorted later)
__global__ void fill_n_kernel(const int* __restrict__ srcn, const int* __restrict__ dstn,
                              const int* __restrict__ start, int* __restrict__ cursor,
                              int* __restrict__ srcs_srt, int* __restrict__ pos) {
    int e = blockIdx.x * blockDim.x + threadIdx.x;
    if (e >= E_EDGE) return;
    int d = dstn[e];
    int p = start[d] + atomicAdd(cursor + d, 1);
    srcs_srt[p] = srcn[e];
    pos[e] = p;
}

// link-graph fill: store packed (src, w) in CSR order
__global__ void fill_l_kernel(const int* __restrict__ srcl, const int* __restrict__ dstl,
                              const float* __restrict__ ew,
                              const int* __restrict__ start, int* __restrict__ cursor,
                              int* __restrict__ srcs_srt, float* __restrict__ w_srt) {
    int e = blockIdx.x * blockDim.x + threadIdx.x;
    if (e >= E_LINKN) return;
    int d = dstl[e];
    int p = start[d] + atomicAdd(cursor + d, 1);
    srcs_srt[p] = srcl[e];
    w_srt[p] = ew[e];
}

// PW[e] = sum_links w*V12[src], wsum[e] = sum w   (pure gather, no atomics)
__global__ void prop1_gather(const float* __restrict__ V12, const int* __restrict__ startl,
                             const int* __restrict__ srcsl, const float* __restrict__ wl,
                             float* __restrict__ PW, float* __restrict__ wsum) {
    int e = blockIdx.x * blockDim.x + threadIdx.x;
    if (e >= E_EDGE) return;
    int s0 = startl[e], s1 = startl[e + 1];
    float acc[12];
#pragma unroll
    for (int j = 0; j < 12; j++) acc[j] = 0.f;
    float ws = 0.f;
    for (int j = s0; j < s1; j++) {
        int s = srcsl[j];
        float w = wl[j];
        const float4* vp = (const float4*)(V12 + (size_t)s*12);
#pragma unroll
        for (int q = 0; q < 3; q++) {
            float4 v = vp[q];
            acc[4*q+0] += w*v.x; acc[4*q+1] += w*v.y;
            acc[4*q+2] += w*v.z; acc[4*q+3] += w*v.w;
        }
        ws += w;
    }
    float4* pw = (float4*)(PW + (size_t)e*12);
#pragma unroll
    for (int q = 0; q < 3; q++)
        pw[q] = make_float4(acc[4*q+0], acc[4*q+1], acc[4*q+2], acc[4*q+3]);
    wsum[e] = ws;
}

// fused: gather P2/wsum2, combine with V0 + PW[:, :6] + wsum, sigmoid -> wk (CSR-sorted write)
__global__ void prop2score_kernel(const float* __restrict__ PW, const float* __restrict__ wsum,
                                  const int* __restrict__ startl, const int* __restrict__ srcsl,
                                  const float* __restrict__ wl, const float* __restrict__ V0,
                                  const float* __restrict__ cvec, const int* __restrict__ posn,
                                  float* __restrict__ wks) {
    __shared__ float sc[24];
    if (threadIdx.x < 24) sc[threadIdx.x] = cvec[threadIdx.x];
    __syncthreads();
    int e = blockIdx.x * blockDim.x + threadIdx.x;
    if (e >= E_EDGE) return;
    int s0 = startl[e], s1 = startl[e + 1];
    float p2[6];
#pragma unroll
    for (int j = 0; j < 6; j++) p2[j] = 0.f;
    float ws2 = 0.f;
    for (int j = s0; j < s1; j++) {
        int s = srcsl[j];
        float w = wl[j];
        const float2* pv = (const float2*)(PW + (size_t)s*12 + 6);
#pragma unroll
        for (int q = 0; q < 3; q++) {
            float2 v = pv[q];
            p2[2*q+0] += w*v.x; p2[2*q+1] += w*v.y;
        }
        ws2 += w * wsum[s];
    }
    float ws1 = wsum[e];
    float S[6];
#pragma unroll
    for (int j = 0; j < 6; j++)
        S[j] = V0[(size_t)e*6 + j] + PW[(size_t)e*12 + j] + p2[j]
             + ws1*sc[6 + j] + ws2*sc[12 + j] + sc[j] + sc[18 + j];
    int p = posn[e];
#pragma unroll
    for (int k = 0; k < 3; k++)
        wks[(size_t)p*3 + k] = 1.f / (1.f + __expf(S[2*k+1] - S[2*k]));
}

// ---------------- temporal projection ----------------
__global__ void temporal_kernel(const float4* __restrict__ h_entity, const float* __restrict__ Wt,
                                const float* __restrict__ bt, float4* __restrict__ h_ent) {
    __shared__ float sw[SEQLEN];
    if (threadIdx.x < SEQLEN) sw[threadIdx.x] = Wt[threadIdx.x];
    __syncthreads();
    int i = blockIdx.x * blockDim.x + threadIdx.x;            // over N*D/4 = 320000
    if (i >= N_NODE*DIM/4) return;
    float b = bt[0];
    float4 acc = make_float4(b, b, b, b);
#pragma unroll 8
    for (int t = 0; t < SEQLEN; t++) {
        float4 v = h_entity[(size_t)t * (N_NODE*DIM/4) + i];
        float w = sw[t];
        acc.x += w*v.x; acc.y += w*v.y; acc.z += w*v.z; acc.w += w*v.w;
    }
    h_ent[i] = acc;
}

// ---------------- fused GCN hop: h_next = P_k(h_cur); out (+)= h_next @ G_k (+ b_gcn if first)
__global__ void hop_kernel(const float* __restrict__ h_cur, float* __restrict__ h_next,
                           float* __restrict__ out,
                           const int* __restrict__ startn, const int* __restrict__ srcs_srt,
                           const float* __restrict__ wks, int k,
                           const float* __restrict__ G, const float* __restrict__ bgcn, int first) {
    int node = blockIdx.x;
    int tid  = threadIdx.x;          // 128
    int s0 = startn[node], s1 = startn[node + 1];
    float acc = 0.f;
    for (int j = s0; j < s1; j++) {
        float w = wks[(size_t)j*3 + k];
        int sn = srcs_srt[j];
        acc += w * h_cur[(size_t)sn*DIM + tid];
    }
    h_next[(size_t)node*DIM + tid] = acc;
    __shared__ float hrow[DIM];
    hrow[tid] = acc;
    __syncthreads();
    float o = first ? bgcn[tid] : out[(size_t)node*DIM + tid];
#pragma unroll 8
    for (int d = 0; d < DIM; d++) o += hrow[d] * G[d*DIM + tid];
    out[(size_t)node*DIM + tid] = o;
}

extern "C" void kernel_launch(void* const* d_in, const int* in_sizes, int n_in,
                              void* d_out, int out_size, void* d_ws, size_t ws_size,
                              hipStream_t stream) {
    const float* h_entity = (const float*)d_in[0];
    const float* x_link   = (const float*)d_in[1];
    const float* ewl      = (const float*)d_in[2];
    const int*   eil      = (const int*)d_in[3];
    const int*   ein      = (const int*)d_in[4];
    const float* Wstart   = (const float*)d_in[5];
    const float* bstart   = (const float*)d_in[6];
    const float* Whl      = (const float*)d_in[7];
    const float* bhl      = (const float*)d_in[8];
    const float* Wec      = (const float*)d_in[9];
    const float* bec      = (const float*)d_in[10];
    const float* Wt       = (const float*)d_in[11];
    const float* bt       = (const float*)d_in[12];
    const float* Wgcn     = (const float*)d_in[13];
    const float* bgcn     = (const float*)d_in[14];
    float* out = (float*)d_out;
    char*  ws  = (char*)d_ws;

    const int* srcl = eil;
    const int* dstl = eil + E_LINKN;
    const int* srcn = ein;
    const int* dstn = ein + E_EDGE;

    int*   degn  = (int*)  (ws + OFF_DEGN);
    int*   curn  = (int*)  (ws + OFF_CURN);
    int*   degl  = (int*)  (ws + OFF_DEGL);
    int*   curl  = (int*)  (ws + OFF_CURL);
    float* Ball  = (float*)(ws + OFF_CONST);
    float* cvec  = Ball + 432;
    float* V0    = (float*)(ws + OFF_V0);
    float* V12   = (float*)(ws + OFF_V12);
    float* PW    = (float*)(ws + OFF_PW);
    float* wsum  = (float*)(ws + OFF_WSUM);
    int*   startn= (int*)  (ws + OFF_STARTN);
    int*   srcsn = (int*)  (ws + OFF_SRCSN);
    int*   posn  = (int*)  (ws + OFF_POSN);
    float* wks   = (float*)(ws + OFF_WKS);
    int*   startl= (int*)  (ws + OFF_STARTL);
    int*   srcsl = (int*)  (ws + OFF_SRCSL);
    float* wl    = (float*)(ws + OFF_WL);
    float* h_ent = (float*)(ws + OFF_HENT);
    float* h_a   = (float*)(ws + OFF_HA);
    float* h_b   = (float*)(ws + OFF_HB);
    int*   partn = (int*)  (ws + OFF_PARTN);  // partials, offs = partn+256
    int*   partl = (int*)  (ws + OFF_PARTL);

    const int nbN = (N_NODE + SCAN_CHUNK - 1) / SCAN_CHUNK;   // 3
    const int nbL = (E_EDGE + SCAN_CHUNK - 1) / SCAN_CHUNK;   // 79

    hipMemsetAsync(ws, 0, ZERO_BYTES, stream);

    consts_kernel<<<1, 256, 0, stream>>>(Wstart, bstart, Whl, bhl, Wec, bec, Ball, cvec);
    v_kernel<<<(E_EDGE + 255)/256, 256, 0, stream>>>(x_link, Ball, V0, V12);

    // CSR builds (hist -> hierarchical scan -> fill)
    hist_kernel<<<(E_EDGE + 255)/256, 256, 0, stream>>>(dstn, degn, E_EDGE);
    hist_kernel<<<(E_LINKN + 255)/256, 256, 0, stream>>>(dstl, degl, E_LINKN);

    partial_kernel<<<nbN, 256, 0, stream>>>(degn, partn, N_NODE);
    scan_partials_kernel<<<1, 256, 0, stream>>>(partn, partn + 256, startn, nbN, N_NODE);
    scan_block_kernel<<<nbN, 256, 0, stream>>>(degn, partn + 256, startn, N_NODE);

    partial_kernel<<<nbL, 256, 0, stream>>>(degl, partl, E_EDGE);
    scan_partials_kernel<<<1, 256, 0, stream>>>(partl, partl + 256, startl, nbL, E_EDGE);
    scan_block_kernel<<<nbL, 256, 0, stream>>>(degl, partl + 256, startl, E_EDGE);

    fill_n_kernel<<<(E_EDGE + 255)/256, 256, 0, stream>>>(srcn, dstn, startn, curn, srcsn, posn);
    fill_l_kernel<<<(E_LINKN + 255)/256, 256, 0, stream>>>(srcl, dstl, ewl, startl, curl, srcsl, wl);

    // link-graph propagates (gather)
    prop1_gather<<<(E_EDGE + 255)/256, 256, 0, stream>>>(V12, startl, srcsl, wl, PW, wsum);
    prop2score_kernel<<<(E_EDGE + 255)/256, 256, 0, stream>>>(PW, wsum, startl, srcsl, wl,
                                                             V0, cvec, posn, wks);

    temporal_kernel<<<(N_NODE*DIM/4 + 255)/256, 256, 0, stream>>>(
        (const float4*)h_entity, Wt, bt, (float4*)h_ent);

    hop_kernel<<<N_NODE, DIM, 0, stream>>>(h_ent, h_a, out, startn, srcsn, wks, 0,
                                           Wgcn + 0*16384, bgcn, 1);
    hop_kernel<<<N_NODE, DIM, 0, stream>>>(h_a, h_b, out, startn, srcsn, wks, 1,
                                           Wgcn + 1*16384, bgcn, 0);
    hop_kernel<<<N_NODE, DIM, 0, stream>>>(h_b, h_ent, out, startn, srcsn, wks, 2,
                                           Wgcn + 2*16384, bgcn, 0);
}